// Round 7
// baseline (397.097 us; speedup 1.0000x reference)
//
#include <hip/hip_runtime.h>
#include <hip/hip_bf16.h>
#include <math.h>

#define N_NODES 65536
#define N_EDGES 524288
#define IN_CH 128
#define HC 64
#define N_GRAPHS 512
#define BUCKET_CAP 64

// ---------------------------------------------------------------------------
// Build per-destination edge buckets. Each entry packs (eid, src) so the
// aggregate kernel needs no second dependent index lookup.
// With E/N = 8 (Poisson), P(deg > 64) ~ 1e-36 per node: cap 64 is safe.
// ---------------------------------------------------------------------------
__global__ void build_buckets(const int* __restrict__ ei, int* __restrict__ cnt,
                              int2* __restrict__ bucket) {
    int e = blockIdx.x * 256 + threadIdx.x;
    if (e >= N_EDGES) return;
    int s = ei[e];                        // src row (coalesced)
    int d = ei[N_EDGES + e];              // dst row (coalesced)
    int pos = atomicAdd(&cnt[d], 1);
    if (pos < BUCKET_CAP) bucket[d * BUCKET_CAP + pos] = make_int2(e, s);
}

// ---------------------------------------------------------------------------
// Fused node GEMM: q = x@Wq+bq, kv (interleaved) = x@{Wk,Wv}+{bk,bv},
// hout = x@Ws+bs (skip). 256 threads/block, 32 nodes/block. Thread =
// (channel c, node-group g); each thread computes 8 nodes x 4 matrices so
// every weight load feeds 8 FMAs. LDS x-reads are wave-uniform broadcasts.
// k and v are interleaved per node (kv[n*128+c], kv[n*128+64+c]) so the
// aggregate kernel's random gather touches one contiguous 512B span.
// ---------------------------------------------------------------------------
template <int FIN>
__global__ __launch_bounds__(256) void node_gemm(
    const float* __restrict__ xin,
    const float* __restrict__ Wq, const float* __restrict__ Wk,
    const float* __restrict__ Wv, const float* __restrict__ Ws,
    const float* __restrict__ bq, const float* __restrict__ bk,
    const float* __restrict__ bv, const float* __restrict__ bs,
    float* __restrict__ q, float* __restrict__ kv,
    float* __restrict__ hout) {
    constexpr int NPB = 32;
    __shared__ float xs[NPB * FIN];
    const int c = threadIdx.x & 63;
    const int g = threadIdx.x >> 6;       // 0..3 -> nodes g*8 .. g*8+7
    const int n0 = blockIdx.x * NPB;

    // float4-vectorized staging (coalesced 16B/lane)
    const float4* xin4 = (const float4*)(xin + (size_t)n0 * FIN);
    float4* xs4 = (float4*)xs;
    for (int i = threadIdx.x; i < NPB * FIN / 4; i += 256)
        xs4[i] = xin4[i];
    __syncthreads();

    float aq[8], ak[8], av[8], as_[8];
#pragma unroll
    for (int t = 0; t < 8; ++t) { aq[t] = 0.f; ak[t] = 0.f; av[t] = 0.f; as_[t] = 0.f; }

    for (int kk = 0; kk < FIN; ++kk) {
        float wq = Wq[kk * HC + c];
        float wk = Wk[kk * HC + c];
        float wv = Wv[kk * HC + c];
        float ws = Ws[kk * HC + c];
#pragma unroll
        for (int t = 0; t < 8; ++t) {
            float xv = xs[(g * 8 + t) * FIN + kk];   // wave-uniform broadcast
            aq[t] = fmaf(xv, wq, aq[t]);
            ak[t] = fmaf(xv, wk, ak[t]);
            av[t] = fmaf(xv, wv, av[t]);
            as_[t] = fmaf(xv, ws, as_[t]);
        }
    }
#pragma unroll
    for (int t = 0; t < 8; ++t) {
        int n = n0 + g * 8 + t;
        q[n * HC + c] = aq[t] + bq[c];
        kv[(size_t)n * 128 + c] = ak[t] + bk[c];
        kv[(size_t)n * 128 + 64 + c] = av[t] + bv[c];
        hout[n * HC + c] = as_[t] + bs[c];
    }
}

// ---------------------------------------------------------------------------
// Per-destination-node aggregation with in-register online softmax.
// One wave (64 lanes) per node; lane = channel; head = lane>>4.
// (eid,src) pairs prefetched lane-parallel in ONE 8B load (lane j holds
// edge j); per-iteration broadcast via readlane (SGPR, saddr-form gathers).
// Edges are processed PAIRWISE: one rescale per pair, two independent
// shuffle-reduce chains (2x ILP), 3 exps/pair instead of 4 — exact
// online-softmax algebra, halved serial chain. 1-pair-ahead prefetch
// overlaps gather latency with the compute chain.
// ---------------------------------------------------------------------------
template <int RELU>
__global__ __launch_bounds__(256) void aggregate(
    const float* __restrict__ q, const float* __restrict__ kv,
    const float* __restrict__ ea,
    const float* __restrict__ We, const float* __restrict__ be,
    const int* __restrict__ cnt,
    const int2* __restrict__ bucket, float* __restrict__ hout) {
    const int wave = threadIdx.x >> 6;
    const int c = threadIdx.x & 63;
    const int n = blockIdx.x * 4 + wave;

    const float qc = q[n * HC + c] * 0.25f;   // fold 1/sqrt(16) into q
    int deg = cnt[n];
    if (deg > BUCKET_CAP) deg = BUCKET_CAP;

    // lane-parallel prefetch of (eid, src) pairs — single 8B load
    int myeid = 0, mysrc = 0;
    if (c < deg) {
        int2 b = bucket[n * BUCKET_CAP + c];
        myeid = b.x;
        mysrc = b.y;
    }

    const float bec = be[c];
    float wec[8];
#pragma unroll
    for (int f = 0; f < 8; ++f) wec[f] = We[f * HC + c];

    float m = -INFINITY, d = 0.f, o = 0.f;

    // edge-slot registers: current pair (A,B) and prefetch pair (nA,nB)
    float4 eA0, eA1, eB0, eB1, nA0, nA1, nB0, nB1;
    float kA, vA, kB, vB, nkA, nvA, nkB, nvB;

#define LOAD_EDGE(idx, E0, E1, KC, VC)                                   \
    {                                                                    \
        int eid_ = __builtin_amdgcn_readlane(myeid, (idx));              \
        int s_   = __builtin_amdgcn_readlane(mysrc, (idx));              \
        E0 = *(const float4*)(ea + (size_t)eid_ * 8);                    \
        E1 = *(const float4*)(ea + (size_t)eid_ * 8 + 4);                \
        KC = kv[(size_t)s_ * 128 + c];                                   \
        VC = kv[(size_t)s_ * 128 + 64 + c];                              \
    }

#define EDGE_PROJ(E0, E1, EC)                                            \
    float EC = bec;                                                      \
    EC = fmaf(E0.x, wec[0], EC); EC = fmaf(E0.y, wec[1], EC);            \
    EC = fmaf(E0.z, wec[2], EC); EC = fmaf(E0.w, wec[3], EC);            \
    EC = fmaf(E1.x, wec[4], EC); EC = fmaf(E1.y, wec[5], EC);            \
    EC = fmaf(E1.z, wec[6], EC); EC = fmaf(E1.w, wec[7], EC);

#define HEAD_REDUCE(P)                                                   \
    P += __shfl_xor(P, 1);  P += __shfl_xor(P, 2);                       \
    P += __shfl_xor(P, 4);  P += __shfl_xor(P, 8);

    const int npairs = deg >> 1;

    // initial fill of the current pair slots
    if (deg >= 2) {
        LOAD_EDGE(0, eA0, eA1, kA, vA);
        LOAD_EDGE(1, eB0, eB1, kB, vB);
    } else if (deg == 1) {
        LOAD_EDGE(0, eA0, eA1, kA, vA);
    }

    for (int p = 0; p < npairs; ++p) {
        // prefetch next pair (or odd tail) while computing current pair
        int base = (p + 1) * 2;
        if (base + 1 < deg) {
            LOAD_EDGE(base, nA0, nA1, nkA, nvA);
            LOAD_EDGE(base + 1, nB0, nB1, nkB, nvB);
        } else if (base < deg) {
            LOAD_EDGE(base, nA0, nA1, nkA, nvA);
        }

        EDGE_PROJ(eA0, eA1, ecA);
        EDGE_PROJ(eB0, eB1, ecB);

        float pA = qc * (kA + ecA);
        float pB = qc * (kB + ecB);
        HEAD_REDUCE(pA);
        HEAD_REDUCE(pB);

        float newm = fmaxf(m, fmaxf(pA, pB));
        float scale = __expf(m - newm);       // exp(-inf)=0 on first pair
        float wA = __expf(pA - newm);
        float wB = __expf(pB - newm);
        d = d * scale + wA + wB;
        o = o * scale + (vA + ecA) * wA + (vB + ecB) * wB;
        m = newm;

        // rotate prefetched slots into current
        eA0 = nA0; eA1 = nA1; kA = nkA; vA = nvA;
        eB0 = nB0; eB1 = nB1; kB = nkB; vB = nvB;
    }

    if (deg & 1) {                            // odd tail edge (in A slot)
        EDGE_PROJ(eA0, eA1, ecA);
        float pA = qc * (kA + ecA);
        HEAD_REDUCE(pA);
        float newm = fmaxf(m, pA);
        float scale = __expf(m - newm);
        float wA = __expf(pA - newm);
        d = d * scale + wA;
        o = o * scale + (vA + ecA) * wA;
    }

#undef LOAD_EDGE
#undef EDGE_PROJ
#undef HEAD_REDUCE

    float msg = (deg > 0) ? (o / d) : 0.f;    // d >= 1 whenever deg > 0
    float val = hout[n * HC + c] + msg;
    if (RELU) val = fmaxf(val, 0.f);
    hout[n * HC + c] = val;
}

// ---------------------------------------------------------------------------
// Mean pool. batch is sorted, so each graph's node range is found by binary
// search; one wave per graph, coalesced row sums with 4-way ILP. No atomics,
// no scratch, no finalize pass.
// ---------------------------------------------------------------------------
__device__ __forceinline__ int lower_bound(const int* __restrict__ b, int val) {
    int lo = 0, hi = N_NODES;
    while (lo < hi) {
        int mid = (lo + hi) >> 1;
        if (b[mid] < val) lo = mid + 1; else hi = mid;
    }
    return lo;
}

__global__ __launch_bounds__(256) void pool_graph(const float* __restrict__ h,
                                                  const int* __restrict__ batch,
                                                  float* __restrict__ out) {
    const int g = blockIdx.x * 4 + (threadIdx.x >> 6);
    const int c = threadIdx.x & 63;
    const int s = lower_bound(batch, g);
    const int e = lower_bound(batch, g + 1);

    float a0 = 0.f, a1 = 0.f, a2 = 0.f, a3 = 0.f;
    int i = s;
    for (; i + 4 <= e; i += 4) {
        a0 += h[(size_t)i * HC + c];
        a1 += h[(size_t)(i + 1) * HC + c];
        a2 += h[(size_t)(i + 2) * HC + c];
        a3 += h[(size_t)(i + 3) * HC + c];
    }
    for (; i < e; ++i) a0 += h[(size_t)i * HC + c];
    float acc = (a0 + a1) + (a2 + a3);
    out[g * HC + c] = acc / fmaxf((float)(e - s), 1.f);
}

// ---------------------------------------------------------------------------
extern "C" void kernel_launch(void* const* d_in, const int* in_sizes, int n_in,
                              void* d_out, int out_size, void* d_ws, size_t ws_size,
                              hipStream_t stream) {
    const float* x     = (const float*)d_in[0];
    const float* ea    = (const float*)d_in[1];
    const int*   ei    = (const int*)d_in[2];
    const int*   batch = (const int*)d_in[3];
    const float* Wq1 = (const float*)d_in[4];
    const float* Wk1 = (const float*)d_in[5];
    const float* Wv1 = (const float*)d_in[6];
    const float* We1 = (const float*)d_in[7];
    const float* Ws1 = (const float*)d_in[8];
    const float* Wq2 = (const float*)d_in[9];
    const float* Wk2 = (const float*)d_in[10];
    const float* Wv2 = (const float*)d_in[11];
    const float* We2 = (const float*)d_in[12];
    const float* Ws2 = (const float*)d_in[13];
    const float* bq1 = (const float*)d_in[14];
    const float* bk1 = (const float*)d_in[15];
    const float* bv1 = (const float*)d_in[16];
    const float* be1 = (const float*)d_in[17];
    const float* bs1 = (const float*)d_in[18];
    const float* bq2 = (const float*)d_in[19];
    const float* bk2 = (const float*)d_in[20];
    const float* bv2 = (const float*)d_in[21];
    const float* be2 = (const float*)d_in[22];
    const float* bs2 = (const float*)d_in[23];
    float* out = (float*)d_out;

    char* ws = (char*)d_ws;
    size_t off = 0;
    auto alloc = [&](size_t bytes) -> void* {
        void* p = ws + off;
        off += (bytes + 255) & ~(size_t)255;
        return p;
    };
    int*   cnt    = (int*)alloc((size_t)N_NODES * 4);
    int2*  bucket = (int2*)alloc((size_t)N_NODES * BUCKET_CAP * 8);
    float* q      = (float*)alloc((size_t)N_NODES * HC * 4);
    float* kv     = (float*)alloc((size_t)N_NODES * 128 * 4);
    float* h1     = (float*)alloc((size_t)N_NODES * HC * 4);
    float* h2     = (float*)alloc((size_t)N_NODES * HC * 4);

    hipMemsetAsync(cnt, 0, (size_t)N_NODES * 4, stream);
    build_buckets<<<N_EDGES / 256, 256, 0, stream>>>(ei, cnt, bucket);

    // ---- layer 1 ----
    node_gemm<IN_CH><<<N_NODES / 32, 256, 0, stream>>>(
        x, Wq1, Wk1, Wv1, Ws1, bq1, bk1, bv1, bs1, q, kv, h1);
    aggregate<1><<<N_NODES / 4, 256, 0, stream>>>(
        q, kv, ea, We1, be1, cnt, bucket, h1);

    // ---- layer 2 ----
    node_gemm<HC><<<N_NODES / 32, 256, 0, stream>>>(
        h1, Wq2, Wk2, Wv2, Ws2, bq2, bk2, bv2, bs2, q, kv, h2);
    aggregate<0><<<N_NODES / 4, 256, 0, stream>>>(
        q, kv, ea, We2, be2, cnt, bucket, h2);

    // ---- mean pool ----
    pool_graph<<<N_GRAPHS / 4, 256, 0, stream>>>(h2, batch, out);
}

// Round 8
// 390.904 us; speedup vs baseline: 1.0158x; 1.0158x over previous
//
#include <hip/hip_runtime.h>
#include <hip/hip_bf16.h>
#include <math.h>

#define N_NODES 65536
#define N_EDGES 524288
#define IN_CH 128
#define HC 64
#define N_GRAPHS 512
#define BUCKET_CAP 64

// ---------------------------------------------------------------------------
// Build per-destination edge buckets. Each entry packs (eid, src) so the
// aggregate kernel needs no second dependent index lookup.
// With E/N = 8 (Poisson), P(deg > 64) ~ 1e-36 per node: cap 64 is safe.
// ---------------------------------------------------------------------------
__global__ void build_buckets(const int* __restrict__ ei, int* __restrict__ cnt,
                              int2* __restrict__ bucket) {
    int e = blockIdx.x * 256 + threadIdx.x;
    if (e >= N_EDGES) return;
    int s = ei[e];                        // src row (coalesced)
    int d = ei[N_EDGES + e];              // dst row (coalesced)
    int pos = atomicAdd(&cnt[d], 1);
    if (pos < BUCKET_CAP) bucket[d * BUCKET_CAP + pos] = make_int2(e, s);
}

// ---------------------------------------------------------------------------
// Fused node GEMM: q = x@Wq+bq, kv (interleaved) = x@{Wk,Wv}+{bk,bv},
// hout = x@Ws+bs (skip). 256 threads/block, 64 nodes/block, 16 nodes/thread
// (halves per-FMA weight re-fetch vs 8/thread: 512 MB total L2 weight
// traffic). x staged in LDS, read as wave-uniform float4 broadcasts
// (ds_read_b128, offsets fold to immediates). Weights double-buffered in
// named A/B register sets (compile-time parity) so the next chunk's 16
// loads overlap the current chunk's 256 FMAs. Bias folded into acc init.
// ---------------------------------------------------------------------------
#define NG_PREFETCH(CHUNK, WQ, WK, WV, WS)                                \
    _Pragma("unroll")                                                     \
    for (int u = 0; u < 4; ++u) {                                         \
        WQ[u] = Wq[((CHUNK) * 4 + u) * HC + c];                           \
        WK[u] = Wk[((CHUNK) * 4 + u) * HC + c];                           \
        WV[u] = Wv[((CHUNK) * 4 + u) * HC + c];                           \
        WS[u] = Ws[((CHUNK) * 4 + u) * HC + c];                           \
    }

#define NG_COMPUTE(CHUNK, WQ, WK, WV, WS)                                 \
    _Pragma("unroll")                                                     \
    for (int t = 0; t < NPT; ++t) {                                       \
        float4 xv = *(const float4*)&xs[(wid * NPT + t) * FIN + (CHUNK) * 4]; \
        aq[t] = fmaf(xv.x, WQ[0], aq[t]);                                 \
        aq[t] = fmaf(xv.y, WQ[1], aq[t]);                                 \
        aq[t] = fmaf(xv.z, WQ[2], aq[t]);                                 \
        aq[t] = fmaf(xv.w, WQ[3], aq[t]);                                 \
        ak[t] = fmaf(xv.x, WK[0], ak[t]);                                 \
        ak[t] = fmaf(xv.y, WK[1], ak[t]);                                 \
        ak[t] = fmaf(xv.z, WK[2], ak[t]);                                 \
        ak[t] = fmaf(xv.w, WK[3], ak[t]);                                 \
        av[t] = fmaf(xv.x, WV[0], av[t]);                                 \
        av[t] = fmaf(xv.y, WV[1], av[t]);                                 \
        av[t] = fmaf(xv.z, WV[2], av[t]);                                 \
        av[t] = fmaf(xv.w, WV[3], av[t]);                                 \
        as_[t] = fmaf(xv.x, WS[0], as_[t]);                               \
        as_[t] = fmaf(xv.y, WS[1], as_[t]);                               \
        as_[t] = fmaf(xv.z, WS[2], as_[t]);                               \
        as_[t] = fmaf(xv.w, WS[3], as_[t]);                               \
    }

template <int FIN>
__global__ __launch_bounds__(256) void node_gemm(
    const float* __restrict__ xin,
    const float* __restrict__ Wq, const float* __restrict__ Wk,
    const float* __restrict__ Wv, const float* __restrict__ Ws,
    const float* __restrict__ bq, const float* __restrict__ bk,
    const float* __restrict__ bv, const float* __restrict__ bs,
    float* __restrict__ q, float* __restrict__ kv,
    float* __restrict__ hout) {
    constexpr int NPB = 64;               // nodes per block
    constexpr int NPT = 16;               // nodes per thread
    constexpr int NCH = FIN / 4;          // 4-wide K chunks
    __shared__ float xs[NPB * FIN];
    const int c = threadIdx.x & 63;       // channel = lane
    const int wid = threadIdx.x >> 6;     // wave -> nodes [wid*16, wid*16+16)
    const int n0 = blockIdx.x * NPB;

    float wAq[4], wAk[4], wAv[4], wAs[4];
    float wBq[4], wBk[4], wBv[4], wBs[4];

    // chunk-0 weight prefetch issues before (and overlaps) LDS staging
    NG_PREFETCH(0, wAq, wAk, wAv, wAs)

    const float4* xin4 = (const float4*)(xin + (size_t)n0 * FIN);
    float4* xs4 = (float4*)xs;
    for (int i = threadIdx.x; i < NPB * FIN / 4; i += 256)
        xs4[i] = xin4[i];

    float aq[NPT], ak[NPT], av[NPT], as_[NPT];
    const float biasq = bq[c], biask = bk[c], biasv = bv[c], biass = bs[c];
#pragma unroll
    for (int t = 0; t < NPT; ++t) {
        aq[t] = biasq; ak[t] = biask; av[t] = biasv; as_[t] = biass;
    }
    __syncthreads();

    for (int kc = 0; kc < NCH; kc += 2) {
        NG_PREFETCH(kc + 1, wBq, wBk, wBv, wBs)
        NG_COMPUTE(kc, wAq, wAk, wAv, wAs)
        if (kc + 2 < NCH) {
            NG_PREFETCH(kc + 2, wAq, wAk, wAv, wAs)
        }
        NG_COMPUTE(kc + 1, wBq, wBk, wBv, wBs)
    }

#pragma unroll
    for (int t = 0; t < NPT; ++t) {
        int n = n0 + wid * NPT + t;
        q[n * HC + c] = aq[t];
        kv[(size_t)n * 128 + c] = ak[t];
        kv[(size_t)n * 128 + 64 + c] = av[t];
        hout[n * HC + c] = as_[t];
    }
}

#undef NG_PREFETCH
#undef NG_COMPUTE

// ---------------------------------------------------------------------------
// Per-destination-node aggregation with in-register online softmax.
// One wave (64 lanes) per node; lane = channel; head = lane>>4.
// (eid,src) pairs prefetched lane-parallel in ONE 8B load (lane j holds
// edge j); per-iteration broadcast via readlane (SGPR, saddr-form gathers).
// Edges are processed PAIRWISE: one rescale per pair, two independent
// shuffle-reduce chains (2x ILP), 3 exps/pair instead of 4 — exact
// online-softmax algebra, halved serial chain. 1-pair-ahead prefetch
// overlaps gather latency with the compute chain.
// ---------------------------------------------------------------------------
template <int RELU>
__global__ __launch_bounds__(256) void aggregate(
    const float* __restrict__ q, const float* __restrict__ kv,
    const float* __restrict__ ea,
    const float* __restrict__ We, const float* __restrict__ be,
    const int* __restrict__ cnt,
    const int2* __restrict__ bucket, float* __restrict__ hout) {
    const int wave = threadIdx.x >> 6;
    const int c = threadIdx.x & 63;
    const int n = blockIdx.x * 4 + wave;

    const float qc = q[n * HC + c] * 0.25f;   // fold 1/sqrt(16) into q
    int deg = cnt[n];
    if (deg > BUCKET_CAP) deg = BUCKET_CAP;

    // lane-parallel prefetch of (eid, src) pairs — single 8B load
    int myeid = 0, mysrc = 0;
    if (c < deg) {
        int2 b = bucket[n * BUCKET_CAP + c];
        myeid = b.x;
        mysrc = b.y;
    }

    const float bec = be[c];
    float wec[8];
#pragma unroll
    for (int f = 0; f < 8; ++f) wec[f] = We[f * HC + c];

    float m = -INFINITY, d = 0.f, o = 0.f;

    // edge-slot registers: current pair (A,B) and prefetch pair (nA,nB)
    float4 eA0, eA1, eB0, eB1, nA0, nA1, nB0, nB1;
    float kA, vA, kB, vB, nkA, nvA, nkB, nvB;

#define LOAD_EDGE(idx, E0, E1, KC, VC)                                   \
    {                                                                    \
        int eid_ = __builtin_amdgcn_readlane(myeid, (idx));              \
        int s_   = __builtin_amdgcn_readlane(mysrc, (idx));              \
        E0 = *(const float4*)(ea + (size_t)eid_ * 8);                    \
        E1 = *(const float4*)(ea + (size_t)eid_ * 8 + 4);                \
        KC = kv[(size_t)s_ * 128 + c];                                   \
        VC = kv[(size_t)s_ * 128 + 64 + c];                              \
    }

#define EDGE_PROJ(E0, E1, EC)                                            \
    float EC = bec;                                                      \
    EC = fmaf(E0.x, wec[0], EC); EC = fmaf(E0.y, wec[1], EC);            \
    EC = fmaf(E0.z, wec[2], EC); EC = fmaf(E0.w, wec[3], EC);            \
    EC = fmaf(E1.x, wec[4], EC); EC = fmaf(E1.y, wec[5], EC);            \
    EC = fmaf(E1.z, wec[6], EC); EC = fmaf(E1.w, wec[7], EC);

#define HEAD_REDUCE(P)                                                   \
    P += __shfl_xor(P, 1);  P += __shfl_xor(P, 2);                       \
    P += __shfl_xor(P, 4);  P += __shfl_xor(P, 8);

    const int npairs = deg >> 1;

    // initial fill of the current pair slots
    if (deg >= 2) {
        LOAD_EDGE(0, eA0, eA1, kA, vA);
        LOAD_EDGE(1, eB0, eB1, kB, vB);
    } else if (deg == 1) {
        LOAD_EDGE(0, eA0, eA1, kA, vA);
    }

    for (int p = 0; p < npairs; ++p) {
        // prefetch next pair (or odd tail) while computing current pair
        int base = (p + 1) * 2;
        if (base + 1 < deg) {
            LOAD_EDGE(base, nA0, nA1, nkA, nvA);
            LOAD_EDGE(base + 1, nB0, nB1, nkB, nvB);
        } else if (base < deg) {
            LOAD_EDGE(base, nA0, nA1, nkA, nvA);
        }

        EDGE_PROJ(eA0, eA1, ecA);
        EDGE_PROJ(eB0, eB1, ecB);

        float pA = qc * (kA + ecA);
        float pB = qc * (kB + ecB);
        HEAD_REDUCE(pA);
        HEAD_REDUCE(pB);

        float newm = fmaxf(m, fmaxf(pA, pB));
        float scale = __expf(m - newm);       // exp(-inf)=0 on first pair
        float wA = __expf(pA - newm);
        float wB = __expf(pB - newm);
        d = d * scale + wA + wB;
        o = o * scale + (vA + ecA) * wA + (vB + ecB) * wB;
        m = newm;

        // rotate prefetched slots into current
        eA0 = nA0; eA1 = nA1; kA = nkA; vA = nvA;
        eB0 = nB0; eB1 = nB1; kB = nkB; vB = nvB;
    }

    if (deg & 1) {                            // odd tail edge (in A slot)
        EDGE_PROJ(eA0, eA1, ecA);
        float pA = qc * (kA + ecA);
        HEAD_REDUCE(pA);
        float newm = fmaxf(m, pA);
        float scale = __expf(m - newm);
        float wA = __expf(pA - newm);
        d = d * scale + wA;
        o = o * scale + (vA + ecA) * wA;
    }

#undef LOAD_EDGE
#undef EDGE_PROJ
#undef HEAD_REDUCE

    float msg = (deg > 0) ? (o / d) : 0.f;    // d >= 1 whenever deg > 0
    float val = hout[n * HC + c] + msg;
    if (RELU) val = fmaxf(val, 0.f);
    hout[n * HC + c] = val;
}

// ---------------------------------------------------------------------------
// Mean pool. batch is sorted, so each graph's node range is found by binary
// search; one wave per graph, coalesced row sums with 4-way ILP. No atomics,
// no scratch, no finalize pass.
// ---------------------------------------------------------------------------
__device__ __forceinline__ int lower_bound(const int* __restrict__ b, int val) {
    int lo = 0, hi = N_NODES;
    while (lo < hi) {
        int mid = (lo + hi) >> 1;
        if (b[mid] < val) lo = mid + 1; else hi = mid;
    }
    return lo;
}

__global__ __launch_bounds__(256) void pool_graph(const float* __restrict__ h,
                                                  const int* __restrict__ batch,
                                                  float* __restrict__ out) {
    const int g = blockIdx.x * 4 + (threadIdx.x >> 6);
    const int c = threadIdx.x & 63;
    const int s = lower_bound(batch, g);
    const int e = lower_bound(batch, g + 1);

    float a0 = 0.f, a1 = 0.f, a2 = 0.f, a3 = 0.f;
    int i = s;
    for (; i + 4 <= e; i += 4) {
        a0 += h[(size_t)i * HC + c];
        a1 += h[(size_t)(i + 1) * HC + c];
        a2 += h[(size_t)(i + 2) * HC + c];
        a3 += h[(size_t)(i + 3) * HC + c];
    }
    for (; i < e; ++i) a0 += h[(size_t)i * HC + c];
    float acc = (a0 + a1) + (a2 + a3);
    out[g * HC + c] = acc / fmaxf((float)(e - s), 1.f);
}

// ---------------------------------------------------------------------------
extern "C" void kernel_launch(void* const* d_in, const int* in_sizes, int n_in,
                              void* d_out, int out_size, void* d_ws, size_t ws_size,
                              hipStream_t stream) {
    const float* x     = (const float*)d_in[0];
    const float* ea    = (const float*)d_in[1];
    const int*   ei    = (const int*)d_in[2];
    const int*   batch = (const int*)d_in[3];
    const float* Wq1 = (const float*)d_in[4];
    const float* Wk1 = (const float*)d_in[5];
    const float* Wv1 = (const float*)d_in[6];
    const float* We1 = (const float*)d_in[7];
    const float* Ws1 = (const float*)d_in[8];
    const float* Wq2 = (const float*)d_in[9];
    const float* Wk2 = (const float*)d_in[10];
    const float* Wv2 = (const float*)d_in[11];
    const float* We2 = (const float*)d_in[12];
    const float* Ws2 = (const float*)d_in[13];
    const float* bq1 = (const float*)d_in[14];
    const float* bk1 = (const float*)d_in[15];
    const float* bv1 = (const float*)d_in[16];
    const float* be1 = (const float*)d_in[17];
    const float* bs1 = (const float*)d_in[18];
    const float* bq2 = (const float*)d_in[19];
    const float* bk2 = (const float*)d_in[20];
    const float* bv2 = (const float*)d_in[21];
    const float* be2 = (const float*)d_in[22];
    const float* bs2 = (const float*)d_in[23];
    float* out = (float*)d_out;

    char* ws = (char*)d_ws;
    size_t off = 0;
    auto alloc = [&](size_t bytes) -> void* {
        void* p = ws + off;
        off += (bytes + 255) & ~(size_t)255;
        return p;
    };
    int*   cnt    = (int*)alloc((size_t)N_NODES * 4);
    int2*  bucket = (int2*)alloc((size_t)N_NODES * BUCKET_CAP * 8);
    float* q      = (float*)alloc((size_t)N_NODES * HC * 4);
    float* kv     = (float*)alloc((size_t)N_NODES * 128 * 4);
    float* h1     = (float*)alloc((size_t)N_NODES * HC * 4);
    float* h2     = (float*)alloc((size_t)N_NODES * HC * 4);

    hipMemsetAsync(cnt, 0, (size_t)N_NODES * 4, stream);
    build_buckets<<<N_EDGES / 256, 256, 0, stream>>>(ei, cnt, bucket);

    // ---- layer 1 ----
    node_gemm<IN_CH><<<N_NODES / 64, 256, 0, stream>>>(
        x, Wq1, Wk1, Wv1, Ws1, bq1, bk1, bv1, bs1, q, kv, h1);
    aggregate<1><<<N_NODES / 4, 256, 0, stream>>>(
        q, kv, ea, We1, be1, cnt, bucket, h1);

    // ---- layer 2 ----
    node_gemm<HC><<<N_NODES / 64, 256, 0, stream>>>(
        h1, Wq2, Wk2, Wv2, Ws2, bq2, bk2, bv2, bs2, q, kv, h2);
    aggregate<0><<<N_NODES / 4, 256, 0, stream>>>(
        q, kv, ea, We2, be2, cnt, bucket, h2);

    // ---- mean pool ----
    pool_graph<<<N_GRAPHS / 4, 256, 0, stream>>>(h2, batch, out);
}